// Round 1
// baseline (412.221 us; speedup 1.0000x reference)
//
#include <hip/hip_runtime.h>

// Transformer block: x[2,2048,768] fp32. All GEMMs in bf16 MFMA (16x16x32),
// fp32 accumulate. Workspace layout (aliased after liveness): ~64.5 MB.

typedef unsigned short u16;
typedef unsigned int u32;
typedef __attribute__((ext_vector_type(8))) short s16x8;   // 8 bf16 (4 VGPR)
typedef __attribute__((ext_vector_type(4))) float fx4;     // 4 fp32 acc

#define D_MODEL 768
#define NH 12
#define HS 64
#define TT 2048
#define BB 2

__device__ __forceinline__ u16 f2bf(float f) {
  union { float f; u32 u; } v; v.f = f;
  u32 r = v.u + 0x7fffu + ((v.u >> 16) & 1u);   // RNE
  return (u16)(r >> 16);
}
__device__ __forceinline__ float bf2f(u16 h) {
  union { u32 u; float f; } v; v.u = ((u32)h) << 16; return v.f;
}

// async global->LDS, 16B per lane; LDS dest = wave-uniform base + lane*16
__device__ __forceinline__ void async16(const void* g, void* l) {
  __builtin_amdgcn_global_load_lds(
      (const __attribute__((address_space(1))) u32*)g,
      (__attribute__((address_space(3))) u32*)l, 16, 0, 0);
}

// ---------------- transpose + fp32->bf16 convert: in[R][C] -> out[C][R] ----
__global__ __launch_bounds__(256) void tconv(const float* __restrict__ in,
                                             u16* __restrict__ out, int R, int C) {
  __shared__ float t[32][33];
  int c0 = blockIdx.x * 32, r0 = blockIdx.y * 32;
  int x = threadIdx.x, y = threadIdx.y;
  for (int i = 0; i < 4; i++)
    t[y + i * 8][x] = in[(size_t)(r0 + y + i * 8) * C + c0 + x];
  __syncthreads();
  for (int i = 0; i < 4; i++)
    out[(size_t)(c0 + y + i * 8) * R + r0 + x] = f2bf(t[x][y + i * 8]);
}

// ---------------- V^T extraction: QKV[4096][2304] -> Vt[24][64][2048] ------
__global__ __launch_bounds__(256) void vt_extract(const u16* __restrict__ qkv,
                                                  u16* __restrict__ vt) {
  __shared__ u16 t[32][33];
  int bh = blockIdx.z, b = bh / NH, h = bh % NH;
  int t0 = blockIdx.x * 32, v0 = blockIdx.y * 32;
  int x = threadIdx.x, y = threadIdx.y;
  for (int i = 0; i < 4; i++)
    t[y + i * 8][x] = qkv[(size_t)(b * TT + t0 + y + i * 8) * 2304 + 1536 + h * HS + v0 + x];
  __syncthreads();
  for (int i = 0; i < 4; i++)
    vt[(size_t)(bh * HS + v0 + y + i * 8) * TT + t0 + x] = t[x][y + i * 8];
}

// ---------------- LayerNorm: fp32 row[768] -> bf16 ------------------------
__global__ __launch_bounds__(256) void ln_kernel(const float* __restrict__ x,
                                                 const float* __restrict__ g,
                                                 const float* __restrict__ bta,
                                                 u16* __restrict__ out) {
  int row = blockIdx.x;
  const float* xr = x + (size_t)row * D_MODEL;
  int tid = threadIdx.x;
  float v0 = xr[tid], v1 = xr[tid + 256], v2 = xr[tid + 512];
  float s = v0 + v1 + v2, sq = v0 * v0 + v1 * v1 + v2 * v2;
  for (int m = 1; m < 64; m <<= 1) { s += __shfl_xor(s, m); sq += __shfl_xor(sq, m); }
  __shared__ float ss[4], ssq[4];
  int w = tid >> 6;
  if ((tid & 63) == 0) { ss[w] = s; ssq[w] = sq; }
  __syncthreads();
  s = ss[0] + ss[1] + ss[2] + ss[3];
  sq = ssq[0] + ssq[1] + ssq[2] + ssq[3];
  float mean = s * (1.f / D_MODEL);
  float var = sq * (1.f / D_MODEL) - mean * mean;
  float rstd = rsqrtf(var + 1e-5f);
  u16* orow = out + (size_t)row * D_MODEL;
  orow[tid]       = f2bf((v0 - mean) * rstd * g[tid]       + bta[tid]);
  orow[tid + 256] = f2bf((v1 - mean) * rstd * g[tid + 256] + bta[tid + 256]);
  orow[tid + 512] = f2bf((v2 - mean) * rstd * g[tid + 512] + bta[tid + 512]);
}

// ---------------- GEMM: C[M][N] = A[M][K](bf16) * Bt[N][K](bf16)^T ---------
// 128x128 tile, BK=32, 4 waves in 2x2, 4x4 16x16x32 MFMA tiles per wave.
// EPI 0: store bf16. EPI 1: fp32 out = acc + res[row][col] + bias[col].
// EPI 2: bf16 out = relu(acc + bias[col]).
template <int EPI>
__global__ __launch_bounds__(256) void gemm_bt(
    const u16* __restrict__ A, const u16* __restrict__ Bt,
    int M, int N, int K,
    u16* __restrict__ outb, float* __restrict__ outf,
    const float* __restrict__ res, const float* __restrict__ bias) {
  __shared__ __align__(16) u16 lA[128 * 32];
  __shared__ __align__(16) u16 lB[128 * 32];
  const int tid = threadIdx.x;
  const int lane = tid & 63, w = tid >> 6;
  const int quad = lane >> 4, l15 = lane & 15;
  const int wm = w >> 1, wn = w & 1;
  const int bm = blockIdx.y, bn = blockIdx.x;

  fx4 acc[4][4] = {};

  for (int kt = 0; kt < K; kt += 32) {
    __syncthreads();
    // stage A tile (128 rows x 32 k, 16B chunks, XOR swizzle q ^ ((m>>1)&3))
    for (int t = 0; t < 2; t++) {
      int p = (w * 2 + t) * 64 + lane;           // physical chunk
      int m = p >> 2, qp = p & 3;
      int ql = qp ^ ((m >> 1) & 3);
      const u16* g = A + (size_t)(bm * 128 + m) * K + kt + ql * 8;
      async16(g, (char*)lA + (w * 2 + t) * 1024);
    }
    for (int t = 0; t < 2; t++) {
      int p = (w * 2 + t) * 64 + lane;
      int n = p >> 2, qp = p & 3;
      int ql = qp ^ ((n >> 1) & 3);
      const u16* g = Bt + (size_t)(bn * 128 + n) * K + kt + ql * 8;
      async16(g, (char*)lB + (w * 2 + t) * 1024);
    }
    __syncthreads();
    s16x8 af[4], bfr[4];
    for (int i = 0; i < 4; i++) {
      int m = wm * 64 + i * 16 + l15;
      int phys = m * 4 + (quad ^ ((m >> 1) & 3));
      af[i] = *(const s16x8*)((const char*)lA + phys * 16);
    }
    for (int j = 0; j < 4; j++) {
      int n = wn * 64 + j * 16 + l15;
      int phys = n * 4 + (quad ^ ((n >> 1) & 3));
      bfr[j] = *(const s16x8*)((const char*)lB + phys * 16);
    }
    for (int i = 0; i < 4; i++)
      for (int j = 0; j < 4; j++)
        acc[i][j] = __builtin_amdgcn_mfma_f32_16x16x32_bf16(af[i], bfr[j], acc[i][j], 0, 0, 0);
  }

  for (int i = 0; i < 4; i++)
    for (int j = 0; j < 4; j++)
      for (int r = 0; r < 4; r++) {
        int row = bm * 128 + wm * 64 + i * 16 + quad * 4 + r;
        int col = bn * 128 + wn * 64 + j * 16 + l15;
        float v = acc[i][j][r];
        if (EPI == 0) {
          outb[(size_t)row * N + col] = f2bf(v);
        } else if (EPI == 1) {
          outf[(size_t)row * N + col] = v + res[(size_t)row * N + col] + bias[col];
        } else {
          outb[(size_t)row * N + col] = f2bf(fmaxf(v + bias[col], 0.f));
        }
      }
}

// ---------------- Flash attention: per block one (b,h) x 64 Q rows ---------
__global__ __launch_bounds__(256) void attn_kernel(
    const u16* __restrict__ qkv, const u16* __restrict__ vt,
    const int* __restrict__ mask, u16* __restrict__ out) {
  __shared__ __align__(16) u16 sQ[64 * 64];       // [qrow][k], 8 chunks/row
  __shared__ __align__(16) u16 sK[32 * 64];       // [key][k],  8 chunks/row
  __shared__ __align__(16) u16 sV[64 * 32];       // [vdim][key], 4 chunks/row
  __shared__ __align__(16) u16 sP[4][16 * 32];    // per-wave P, 4 chunks/row
  const int bh = blockIdx.y, b = bh / NH, h = bh % NH;
  const int qt = blockIdx.x;
  const int tid = threadIdx.x, lane = tid & 63, w = tid >> 6;
  const int quad = lane >> 4, l15 = lane & 15;

  // stage Q tile (64x64): swizzle q ^ (m&7)
  for (int t = 0; t < 2; t++) {
    int p = (w * 2 + t) * 64 + lane;
    int m = p >> 3, qp = p & 7, ql = qp ^ (m & 7);
    const u16* g = qkv + (size_t)(b * TT + qt * 64 + m) * 2304 + h * HS + ql * 8;
    async16(g, (char*)sQ + (w * 2 + t) * 1024);
  }
  __syncthreads();
  s16x8 aq[2];
  for (int kk = 0; kk < 2; kk++) {
    int m = w * 16 + l15;
    int q = kk * 4 + quad;
    int phys = m * 8 + (q ^ (m & 7));
    aq[kk] = *(const s16x8*)((const char*)sQ + phys * 16);
  }

  float mrow[4], lrow[4];
  fx4 o[4] = {};
  for (int r = 0; r < 4; r++) { mrow[r] = -INFINITY; lrow[r] = 0.f; }
  const float scale = 0.03608439182435161f;  // 768^-0.5

  for (int kc = 0; kc < TT / 32; kc++) {
    __syncthreads();
    {  // stage K chunk (32 keys x 64)
      int p = w * 64 + lane;
      int m = p >> 3, qp = p & 7, ql = qp ^ (m & 7);
      const u16* g = qkv + (size_t)(b * TT + kc * 32 + m) * 2304 + D_MODEL + h * HS + ql * 8;
      async16(g, (char*)sK + w * 1024);
    }
    {  // stage V^T chunk (64 vdim x 32 keys)
      int p = w * 64 + lane;
      int m = p >> 2, qp = p & 3, ql = qp ^ ((m >> 1) & 3);
      const u16* g = vt + (size_t)bh * HS * TT + (size_t)m * TT + kc * 32 + ql * 8;
      async16(g, (char*)sV + w * 1024);
    }
    __syncthreads();
    // S = Q K^T for this wave's 16 rows x 32 keys
    fx4 s[2] = {};
    for (int jn = 0; jn < 2; jn++)
      for (int kk = 0; kk < 2; kk++) {
        int n = jn * 16 + l15;
        int q = kk * 4 + quad;
        int phys = n * 8 + (q ^ (n & 7));
        s16x8 bk = *(const s16x8*)((const char*)sK + phys * 16);
        s[jn] = __builtin_amdgcn_mfma_f32_16x16x32_bf16(aq[kk], bk, s[jn], 0, 0, 0);
      }
    // scale + mask + online softmax (rows = quad*4+r, cols = lane&15)
    float pv[2][4], mx[4];
    for (int r = 0; r < 4; r++) mx[r] = -INFINITY;
    for (int jn = 0; jn < 2; jn++) {
      int key = kc * 32 + jn * 16 + l15;
      bool dead = (mask[b * TT + key] == 0);
      for (int r = 0; r < 4; r++) {
        float v = s[jn][r] * scale;
        if (dead) v = -1e30f;
        pv[jn][r] = v;
        mx[r] = fmaxf(mx[r], v);
      }
    }
    for (int mm = 1; mm < 16; mm <<= 1)
      for (int r = 0; r < 4; r++) mx[r] = fmaxf(mx[r], __shfl_xor(mx[r], mm));
    float alpha[4], rs[4];
    for (int r = 0; r < 4; r++) {
      float mn = fmaxf(mrow[r], mx[r]);
      alpha[r] = __expf(mrow[r] - mn);
      mrow[r] = mn;
      float e0 = __expf(pv[0][r] - mn), e1 = __expf(pv[1][r] - mn);
      pv[0][r] = e0; pv[1][r] = e1;
      rs[r] = e0 + e1;
    }
    for (int mm = 1; mm < 16; mm <<= 1)
      for (int r = 0; r < 4; r++) rs[r] += __shfl_xor(rs[r], mm);
    for (int r = 0; r < 4; r++) lrow[r] = lrow[r] * alpha[r] + rs[r];
    for (int jv = 0; jv < 4; jv++) {
      fx4 t = o[jv];
      for (int r = 0; r < 4; r++) t[r] *= alpha[r];
      o[jv] = t;
    }
    // P (C-layout) -> LDS in A-layout rows [m][key32], swizzled
    for (int jn = 0; jn < 2; jn++)
      for (int r = 0; r < 4; r++) {
        int row = quad * 4 + r;
        int k = jn * 16 + l15;
        int qp = (k >> 3) ^ ((row >> 1) & 3);
        sP[w][row * 32 + qp * 8 + (k & 7)] = f2bf(pv[jn][r]);
      }
    // same-wave LDS RAW: compiler inserts lgkmcnt wait, no barrier needed
    s16x8 ap;
    {
      int m = l15;
      int phys = m * 4 + (quad ^ ((m >> 1) & 3));
      ap = *(const s16x8*)((const char*)sP[w] + phys * 16);
    }
    for (int jv = 0; jv < 4; jv++) {
      int n = jv * 16 + l15;
      int phys = n * 4 + (quad ^ ((n >> 1) & 3));
      s16x8 bv = *(const s16x8*)((const char*)sV + phys * 16);
      o[jv] = __builtin_amdgcn_mfma_f32_16x16x32_bf16(ap, bv, o[jv], 0, 0, 0);
    }
  }
  for (int jv = 0; jv < 4; jv++)
    for (int r = 0; r < 4; r++) {
      int tokl = qt * 64 + w * 16 + quad * 4 + r;
      float v = o[jv][r] / lrow[r];
      out[(size_t)(b * TT + tokl) * D_MODEL + h * HS + jv * 16 + l15] = f2bf(v);
    }
}

extern "C" void kernel_launch(void* const* d_in, const int* in_sizes, int n_in,
                              void* d_out, int out_size, void* d_ws, size_t ws_size,
                              hipStream_t stream) {
  const float* x    = (const float*)d_in[0];
  const int*   mask = (const int*)d_in[1];
  const float* Wq   = (const float*)d_in[2];
  const float* Wk   = (const float*)d_in[3];
  const float* Wv   = (const float*)d_in[4];
  const float* Wo   = (const float*)d_in[5];
  const float* bo   = (const float*)d_in[6];
  const float* g1   = (const float*)d_in[7];
  const float* be1  = (const float*)d_in[8];
  const float* g2   = (const float*)d_in[9];
  const float* be2  = (const float*)d_in[10];
  const float* W1   = (const float*)d_in[11];
  const float* bb1  = (const float*)d_in[12];
  const float* W2   = (const float*)d_in[13];
  const float* bb2  = (const float*)d_in[14];
  float* out = (float*)d_out;
  char* ws = (char*)d_ws;

  // workspace carve (bytes)
  u16*   WqkvT = (u16*)(ws + 0);                    //  3,538,944  [2304][768]
  u16*   WoT   = (u16*)(ws + 3538944);              //  1,179,648  [768][768]
  u16*   W1T   = (u16*)(ws + 4718592);              //  4,718,592  [3072][768]
  u16*   W2T   = (u16*)(ws + 9437184);              //  4,718,592  [768][3072]
  u16*   h1    = (u16*)(ws + 14155776);             //  6,291,456  [4096][768] (h2 aliases)
  u16*   QKV   = (u16*)(ws + 20447232);             // 18,874,368  [4096][2304] (ff1 aliases)
  u16*   Vt    = (u16*)(ws + 39321600);             //  6,291,456  [24][64][2048]
  u16*   attn  = (u16*)(ws + 45613056);             //  6,291,456  [4096][768]
  float* yv    = (float*)(ws + 51904512);           // 12,582,912  [4096][768]
  u16*   h2    = h1;
  u16*   ff1   = QKV;                               // 25,165,824 spans QKV+Vt

  dim3 tb(32, 8);
  // weights -> bf16 transposed
  tconv<<<dim3(24, 24), tb, 0, stream>>>(Wq, WqkvT,             768, 768);
  tconv<<<dim3(24, 24), tb, 0, stream>>>(Wk, WqkvT + 768 * 768, 768, 768);
  tconv<<<dim3(24, 24), tb, 0, stream>>>(Wv, WqkvT + 1536 * 768, 768, 768);
  tconv<<<dim3(24, 24), tb, 0, stream>>>(Wo, WoT, 768, 768);
  tconv<<<dim3(96, 24), tb, 0, stream>>>(W1, W1T, 768, 3072);
  tconv<<<dim3(24, 96), tb, 0, stream>>>(W2, W2T, 3072, 768);

  ln_kernel<<<4096, 256, 0, stream>>>(x, g1, be1, h1);
  gemm_bt<0><<<dim3(18, 32), 256, 0, stream>>>(h1, WqkvT, 4096, 2304, 768,
                                               QKV, nullptr, nullptr, nullptr);
  vt_extract<<<dim3(64, 2, 24), tb, 0, stream>>>(QKV, Vt);
  attn_kernel<<<dim3(32, 24), 256, 0, stream>>>(QKV, Vt, mask, attn);
  gemm_bt<1><<<dim3(6, 32), 256, 0, stream>>>(attn, WoT, 4096, 768, 768,
                                              nullptr, yv, x, bo);
  ln_kernel<<<4096, 256, 0, stream>>>(yv, g2, be2, h2);
  gemm_bt<2><<<dim3(24, 32), 256, 0, stream>>>(h2, W1T, 4096, 3072, 768,
                                               ff1, nullptr, nullptr, bb1);
  gemm_bt<1><<<dim3(6, 32), 256, 0, stream>>>(ff1, W2T, 4096, 768, 3072,
                                              nullptr, out, yv, bb2);
}

// Round 2
// 349.980 us; speedup vs baseline: 1.1778x; 1.1778x over previous
//
#include <hip/hip_runtime.h>

// Transformer block: x[2,2048,768] fp32. All GEMMs in bf16 MFMA (16x16x32),
// fp32 accumulate. Attention: fixed-shift softmax in log2 domain (scale and
// log2e folded into Q at the QKV-GEMM epilogue; mask folded into MFMA C-init).

typedef unsigned short u16;
typedef unsigned int u32;
typedef __attribute__((ext_vector_type(8))) short s16x8;   // 8 bf16 (4 VGPR)
typedef __attribute__((ext_vector_type(4))) float fx4;     // 4 fp32 acc

#define D_MODEL 768
#define NH 12
#define HS 64
#define TT 2048
#define BB 2

__device__ __forceinline__ u16 f2bf(float f) {
  union { float f; u32 u; } v; v.f = f;
  u32 r = v.u + 0x7fffu + ((v.u >> 16) & 1u);   // RNE
  return (u16)(r >> 16);
}
__device__ __forceinline__ float bf2f(u16 h) {
  union { u32 u; float f; } v; v.u = ((u32)h) << 16; return v.f;
}

// async global->LDS, 16B per lane; LDS dest = wave-uniform base + lane*16
__device__ __forceinline__ void async16(const void* g, void* l) {
  __builtin_amdgcn_global_load_lds(
      (const __attribute__((address_space(1))) u32*)g,
      (__attribute__((address_space(3))) u32*)l, 16, 0, 0);
}

// ---------------- transpose + fp32->bf16 convert: in[R][C] -> out[C][R] ----
__global__ __launch_bounds__(256) void tconv(const float* __restrict__ in,
                                             u16* __restrict__ out, int R, int C) {
  __shared__ float t[32][33];
  int c0 = blockIdx.x * 32, r0 = blockIdx.y * 32;
  int x = threadIdx.x, y = threadIdx.y;
  for (int i = 0; i < 4; i++)
    t[y + i * 8][x] = in[(size_t)(r0 + y + i * 8) * C + c0 + x];
  __syncthreads();
  for (int i = 0; i < 4; i++)
    out[(size_t)(c0 + y + i * 8) * R + r0 + x] = f2bf(t[x][y + i * 8]);
}

// ---------------- V^T extraction: QKV[4096][2304] -> Vt[24][64][2048] ------
__global__ __launch_bounds__(256) void vt_extract(const u16* __restrict__ qkv,
                                                  u16* __restrict__ vt) {
  __shared__ u16 t[32][33];
  int bh = blockIdx.z, b = bh / NH, h = bh % NH;
  int t0 = blockIdx.x * 32, v0 = blockIdx.y * 32;
  int x = threadIdx.x, y = threadIdx.y;
  for (int i = 0; i < 4; i++)
    t[y + i * 8][x] = qkv[(size_t)(b * TT + t0 + y + i * 8) * 2304 + 1536 + h * HS + v0 + x];
  __syncthreads();
  for (int i = 0; i < 4; i++)
    vt[(size_t)(bh * HS + v0 + y + i * 8) * TT + t0 + x] = t[x][y + i * 8];
}

// ---------------- mask -> additive bias (log2 domain) ----------------------
__global__ __launch_bounds__(256) void maskbias(const int* __restrict__ mask,
                                                float* __restrict__ mb) {
  int i = blockIdx.x * 256 + threadIdx.x;
  mb[i] = mask[i] ? 0.f : -1e30f;
}

// ---------------- LayerNorm: fp32 row[768] -> bf16 ------------------------
__global__ __launch_bounds__(256) void ln_kernel(const float* __restrict__ x,
                                                 const float* __restrict__ g,
                                                 const float* __restrict__ bta,
                                                 u16* __restrict__ out) {
  int row = blockIdx.x;
  const float* xr = x + (size_t)row * D_MODEL;
  int tid = threadIdx.x;
  float v0 = xr[tid], v1 = xr[tid + 256], v2 = xr[tid + 512];
  float s = v0 + v1 + v2, sq = v0 * v0 + v1 * v1 + v2 * v2;
  for (int m = 1; m < 64; m <<= 1) { s += __shfl_xor(s, m); sq += __shfl_xor(sq, m); }
  __shared__ float ss[4], ssq[4];
  int w = tid >> 6;
  if ((tid & 63) == 0) { ss[w] = s; ssq[w] = sq; }
  __syncthreads();
  s = ss[0] + ss[1] + ss[2] + ss[3];
  sq = ssq[0] + ssq[1] + ssq[2] + ssq[3];
  float mean = s * (1.f / D_MODEL);
  float var = sq * (1.f / D_MODEL) - mean * mean;
  float rstd = rsqrtf(var + 1e-5f);
  u16* orow = out + (size_t)row * D_MODEL;
  orow[tid]       = f2bf((v0 - mean) * rstd * g[tid]       + bta[tid]);
  orow[tid + 256] = f2bf((v1 - mean) * rstd * g[tid + 256] + bta[tid + 256]);
  orow[tid + 512] = f2bf((v2 - mean) * rstd * g[tid + 512] + bta[tid + 512]);
}

// ---------------- GEMM: C[M][N] = A[M][K](bf16) * Bt[N][K](bf16)^T ---------
// 128x128 tile, BK=32, 4 waves in 2x2, 4x4 16x16x32 MFMA tiles per wave.
// EPI 0: store bf16 (cols < qn scaled by qs). EPI 1: fp32 out = acc+res+bias.
// EPI 2: bf16 out = relu(acc + bias[col]).
template <int EPI>
__global__ __launch_bounds__(256) void gemm_bt(
    const u16* __restrict__ A, const u16* __restrict__ Bt,
    int M, int N, int K,
    u16* __restrict__ outb, float* __restrict__ outf,
    const float* __restrict__ res, const float* __restrict__ bias,
    float qs, int qn) {
  __shared__ __align__(16) u16 lA[128 * 32];
  __shared__ __align__(16) u16 lB[128 * 32];
  const int tid = threadIdx.x;
  const int lane = tid & 63, w = tid >> 6;
  const int quad = lane >> 4, l15 = lane & 15;
  const int wm = w >> 1, wn = w & 1;
  const int bm = blockIdx.y, bn = blockIdx.x;

  fx4 acc[4][4] = {};

  for (int kt = 0; kt < K; kt += 32) {
    __syncthreads();
    for (int t = 0; t < 2; t++) {
      int p = (w * 2 + t) * 64 + lane;
      int m = p >> 2, qp = p & 3;
      int ql = qp ^ ((m >> 1) & 3);
      const u16* g = A + (size_t)(bm * 128 + m) * K + kt + ql * 8;
      async16(g, (char*)lA + (w * 2 + t) * 1024);
    }
    for (int t = 0; t < 2; t++) {
      int p = (w * 2 + t) * 64 + lane;
      int n = p >> 2, qp = p & 3;
      int ql = qp ^ ((n >> 1) & 3);
      const u16* g = Bt + (size_t)(bn * 128 + n) * K + kt + ql * 8;
      async16(g, (char*)lB + (w * 2 + t) * 1024);
    }
    __syncthreads();
    s16x8 af[4], bfr[4];
    for (int i = 0; i < 4; i++) {
      int m = wm * 64 + i * 16 + l15;
      int phys = m * 4 + (quad ^ ((m >> 1) & 3));
      af[i] = *(const s16x8*)((const char*)lA + phys * 16);
    }
    for (int j = 0; j < 4; j++) {
      int n = wn * 64 + j * 16 + l15;
      int phys = n * 4 + (quad ^ ((n >> 1) & 3));
      bfr[j] = *(const s16x8*)((const char*)lB + phys * 16);
    }
    for (int i = 0; i < 4; i++)
      for (int j = 0; j < 4; j++)
        acc[i][j] = __builtin_amdgcn_mfma_f32_16x16x32_bf16(af[i], bfr[j], acc[i][j], 0, 0, 0);
  }

  for (int i = 0; i < 4; i++)
    for (int j = 0; j < 4; j++)
      for (int r = 0; r < 4; r++) {
        int row = bm * 128 + wm * 64 + i * 16 + quad * 4 + r;
        int col = bn * 128 + wn * 64 + j * 16 + l15;
        float v = acc[i][j][r];
        if (EPI == 0) {
          float vv = (col < qn) ? v * qs : v;
          outb[(size_t)row * N + col] = f2bf(vv);
        } else if (EPI == 1) {
          outf[(size_t)row * N + col] = v + res[(size_t)row * N + col] + bias[col];
        } else {
          outb[(size_t)row * N + col] = f2bf(fmaxf(v + bias[col], 0.f));
        }
      }
}

// ---------------- Flash attention (fixed-shift softmax, log2 domain) -------
// One block = one (b,h) x 64 Q rows; KV chunk = 64 keys; 32 iterations.
// Q already prescaled by 768^-0.5 * log2(e); mask enters via MFMA C-init.
__global__ __launch_bounds__(256) void attn_kernel(
    const u16* __restrict__ qkv, const u16* __restrict__ vt,
    const float* __restrict__ maskadd, u16* __restrict__ out) {
  __shared__ __align__(16) u16 sQ[64 * 64];       // [qrow][hs], 8 chunks/row
  __shared__ __align__(16) u16 sK[64 * 64];       // [key][hs]
  __shared__ __align__(16) u16 sV[64 * 64];       // [vdim][key]
  __shared__ __align__(16) u16 sP[4][16 * 64];    // per-wave P [qrow][key]
  const int bh = blockIdx.y, b = bh / NH, h = bh % NH;
  const int qt = blockIdx.x;
  const int tid = threadIdx.x, lane = tid & 63, w = tid >> 6;
  const int quad = lane >> 4, l15 = lane & 15;

  // stage Q tile (64x64), swizzle chunk q ^ (m&7)
  for (int t = 0; t < 2; t++) {
    int p = (w * 2 + t) * 64 + lane;
    int m = p >> 3, qp = p & 7, ql = qp ^ (m & 7);
    async16(qkv + (size_t)(b * TT + qt * 64 + m) * 2304 + h * HS + ql * 8,
            (char*)sQ + (w * 2 + t) * 1024);
  }
  __syncthreads();
  s16x8 aq[2];
  for (int kk = 0; kk < 2; kk++) {
    int m = w * 16 + l15;
    int q = kk * 4 + quad;
    int phys = m * 8 + (q ^ (m & 7));
    aq[kk] = *(const s16x8*)((const char*)sQ + phys * 16);
  }

  float lsum[4] = {0.f, 0.f, 0.f, 0.f};
  fx4 o[4] = {};

  for (int kc = 0; kc < TT / 64; kc++) {
    __syncthreads();
    for (int t = 0; t < 2; t++) {  // stage K chunk (64 keys x 64)
      int p = (w * 2 + t) * 64 + lane;
      int m = p >> 3, qp = p & 7, ql = qp ^ (m & 7);
      async16(qkv + (size_t)(b * TT + kc * 64 + m) * 2304 + D_MODEL + h * HS + ql * 8,
              (char*)sK + (w * 2 + t) * 1024);
    }
    for (int t = 0; t < 2; t++) {  // stage V^T chunk (64 vdim x 64 keys)
      int p = (w * 2 + t) * 64 + lane;
      int m = p >> 3, qp = p & 7, ql = qp ^ (m & 7);
      async16(vt + (size_t)bh * HS * TT + (size_t)m * TT + kc * 64 + ql * 8,
              (char*)sV + (w * 2 + t) * 1024);
    }
    __syncthreads();

    // S = Q K^T (already log2-scaled) + maskbias via C-init; P = exp2(S)
    for (int jn = 0; jn < 4; jn++) {
      float mb = maskadd[b * TT + kc * 64 + jn * 16 + l15];
      fx4 s = {mb, mb, mb, mb};
      for (int kk = 0; kk < 2; kk++) {
        int n = jn * 16 + l15;
        int phys = n * 8 + ((kk * 4 + quad) ^ (n & 7));
        s16x8 bk = *(const s16x8*)((const char*)sK + phys * 16);
        s = __builtin_amdgcn_mfma_f32_16x16x32_bf16(aq[kk], bk, s, 0, 0, 0);
      }
      for (int r = 0; r < 4; r++) {
        float p = __builtin_amdgcn_exp2f(s[r]);
        u16 pb = f2bf(p);
        lsum[r] += bf2f(pb);        // match bf16-rounded P for consistency
        int row = quad * 4 + r, k = jn * 16 + l15;
        sP[w][row * 64 + ((k >> 3) ^ (row & 7)) * 8 + (k & 7)] = pb;
      }
    }
    // same-wave LDS RAW: compiler inserts lgkmcnt wait, no barrier needed
    for (int kk = 0; kk < 2; kk++) {
      int m = l15;
      int phys = m * 8 + ((kk * 4 + quad) ^ (m & 7));
      s16x8 ap = *(const s16x8*)((const char*)sP[w] + phys * 16);
      for (int jv = 0; jv < 4; jv++) {
        int n = jv * 16 + l15;
        int ph2 = n * 8 + ((kk * 4 + quad) ^ (n & 7));
        s16x8 bv = *(const s16x8*)((const char*)sV + ph2 * 16);
        o[jv] = __builtin_amdgcn_mfma_f32_16x16x32_bf16(ap, bv, o[jv], 0, 0, 0);
      }
    }
  }

  // one final row-sum reduction across the 16 lanes of each quad
  for (int mm = 1; mm < 16; mm <<= 1)
    for (int r = 0; r < 4; r++) lsum[r] += __shfl_xor(lsum[r], mm);

  for (int jv = 0; jv < 4; jv++)
    for (int r = 0; r < 4; r++) {
      int tok = qt * 64 + w * 16 + quad * 4 + r;
      out[(size_t)(b * TT + tok) * D_MODEL + h * HS + jv * 16 + l15] =
          f2bf(o[jv][r] / lsum[r]);
    }
}

extern "C" void kernel_launch(void* const* d_in, const int* in_sizes, int n_in,
                              void* d_out, int out_size, void* d_ws, size_t ws_size,
                              hipStream_t stream) {
  const float* x    = (const float*)d_in[0];
  const int*   mask = (const int*)d_in[1];
  const float* Wq   = (const float*)d_in[2];
  const float* Wk   = (const float*)d_in[3];
  const float* Wv   = (const float*)d_in[4];
  const float* Wo   = (const float*)d_in[5];
  const float* bo   = (const float*)d_in[6];
  const float* g1   = (const float*)d_in[7];
  const float* be1  = (const float*)d_in[8];
  const float* g2   = (const float*)d_in[9];
  const float* be2  = (const float*)d_in[10];
  const float* W1   = (const float*)d_in[11];
  const float* bb1  = (const float*)d_in[12];
  const float* W2   = (const float*)d_in[13];
  const float* bb2  = (const float*)d_in[14];
  float* out = (float*)d_out;
  char* ws = (char*)d_ws;

  // workspace carve (bytes)
  u16*   WqkvT = (u16*)(ws + 0);                    //  3,538,944  [2304][768]
  u16*   WoT   = (u16*)(ws + 3538944);              //  1,179,648  [768][768]
  u16*   W1T   = (u16*)(ws + 4718592);              //  4,718,592  [3072][768]
  u16*   W2T   = (u16*)(ws + 9437184);              //  4,718,592  [768][3072]
  u16*   h1    = (u16*)(ws + 14155776);             //  6,291,456  [4096][768] (h2 aliases)
  u16*   QKV   = (u16*)(ws + 20447232);             // 18,874,368  [4096][2304] (ff1 aliases)
  u16*   Vt    = (u16*)(ws + 39321600);             //  6,291,456  [24][64][2048]
  u16*   attn  = (u16*)(ws + 45613056);             //  6,291,456  [4096][768]
  float* yv    = (float*)(ws + 51904512);           // 12,582,912  [4096][768]
  float* mbias = yv;                                // aliases yv: dead before Wo-GEMM writes yv
  u16*   h2    = h1;
  u16*   ff1   = QKV;                               // 25,165,824 spans QKV+Vt

  const float QS = 0.05205875399f;  // 768^-0.5 * log2(e)

  dim3 tb(32, 8);
  tconv<<<dim3(24, 24), tb, 0, stream>>>(Wq, WqkvT,              768, 768);
  tconv<<<dim3(24, 24), tb, 0, stream>>>(Wk, WqkvT + 768 * 768,  768, 768);
  tconv<<<dim3(24, 24), tb, 0, stream>>>(Wv, WqkvT + 1536 * 768, 768, 768);
  tconv<<<dim3(24, 24), tb, 0, stream>>>(Wo, WoT, 768, 768);
  tconv<<<dim3(96, 24), tb, 0, stream>>>(W1, W1T, 768, 3072);
  tconv<<<dim3(24, 96), tb, 0, stream>>>(W2, W2T, 3072, 768);
  maskbias<<<16, 256, 0, stream>>>(mask, mbias);

  ln_kernel<<<4096, 256, 0, stream>>>(x, g1, be1, h1);
  gemm_bt<0><<<dim3(18, 32), 256, 0, stream>>>(h1, WqkvT, 4096, 2304, 768,
                                               QKV, nullptr, nullptr, nullptr, QS, 768);
  vt_extract<<<dim3(64, 2, 24), tb, 0, stream>>>(QKV, Vt);
  attn_kernel<<<dim3(32, 24), 256, 0, stream>>>(QKV, Vt, mbias, attn);
  gemm_bt<1><<<dim3(6, 32), 256, 0, stream>>>(attn, WoT, 4096, 768, 768,
                                              nullptr, yv, x, bo, 1.f, 0);
  ln_kernel<<<4096, 256, 0, stream>>>(yv, g2, be2, h2);
  gemm_bt<2><<<dim3(24, 32), 256, 0, stream>>>(h2, W1T, 4096, 3072, 768,
                                               ff1, nullptr, nullptr, bb1, 1.f, 0);
  gemm_bt<1><<<dim3(6, 32), 256, 0, stream>>>(ff1, W2T, 4096, 768, 3072,
                                              nullptr, out, yv, bb2, 1.f, 0);
}

// Round 3
// 319.188 us; speedup vs baseline: 1.2915x; 1.0965x over previous
//
#include <hip/hip_runtime.h>

// Transformer block: x[2,2048,768] fp32. All GEMMs in bf16 MFMA (16x16x32),
// fp32 accumulate. N=768 GEMMs (Wo, FF2) use split-K with bf16 partials to
// reach >=2.25 blocks/CU; reducers fuse residual+bias (+LN2 for Wo).

typedef unsigned short u16;
typedef unsigned int u32;
typedef __attribute__((ext_vector_type(8))) short s16x8;   // 8 bf16 (4 VGPR)
typedef __attribute__((ext_vector_type(4))) float fx4;     // 4 fp32 acc

#define D_MODEL 768
#define NH 12
#define HS 64
#define TT 2048
#define BB 2

__device__ __forceinline__ u16 f2bf(float f) {
  union { float f; u32 u; } v; v.f = f;
  u32 r = v.u + 0x7fffu + ((v.u >> 16) & 1u);   // RNE
  return (u16)(r >> 16);
}
__device__ __forceinline__ float bf2f(u16 h) {
  union { u32 u; float f; } v; v.u = ((u32)h) << 16; return v.f;
}

// async global->LDS, 16B per lane; LDS dest = wave-uniform base + lane*16
__device__ __forceinline__ void async16(const void* g, void* l) {
  __builtin_amdgcn_global_load_lds(
      (const __attribute__((address_space(1))) u32*)g,
      (__attribute__((address_space(3))) u32*)l, 16, 0, 0);
}

// ---------------- transpose + fp32->bf16 convert: in[R][C] -> out[C][R] ----
__global__ __launch_bounds__(256) void tconv(const float* __restrict__ in,
                                             u16* __restrict__ out, int R, int C) {
  __shared__ float t[32][33];
  int c0 = blockIdx.x * 32, r0 = blockIdx.y * 32;
  int x = threadIdx.x, y = threadIdx.y;
  for (int i = 0; i < 4; i++)
    t[y + i * 8][x] = in[(size_t)(r0 + y + i * 8) * C + c0 + x];
  __syncthreads();
  for (int i = 0; i < 4; i++)
    out[(size_t)(c0 + y + i * 8) * R + r0 + x] = f2bf(t[x][y + i * 8]);
}

// three 768x768 transposes in one launch (z selects Wq/Wk/Wv)
__global__ __launch_bounds__(256) void tconv3(const float* __restrict__ w0,
                                              const float* __restrict__ w1,
                                              const float* __restrict__ w2,
                                              u16* __restrict__ out) {
  __shared__ float t[32][33];
  const float* in = blockIdx.z == 0 ? w0 : blockIdx.z == 1 ? w1 : w2;
  u16* o = out + (size_t)blockIdx.z * 768 * 768;
  int c0 = blockIdx.x * 32, r0 = blockIdx.y * 32;
  int x = threadIdx.x, y = threadIdx.y;
  for (int i = 0; i < 4; i++)
    t[y + i * 8][x] = in[(size_t)(r0 + y + i * 8) * 768 + c0 + x];
  __syncthreads();
  for (int i = 0; i < 4; i++)
    o[(size_t)(c0 + y + i * 8) * 768 + r0 + x] = f2bf(t[x][y + i * 8]);
}

// ---------------- V^T extraction: QKV[4096][2304] -> Vt[24][64][2048] ------
__global__ __launch_bounds__(256) void vt_extract(const u16* __restrict__ qkv,
                                                  u16* __restrict__ vt) {
  __shared__ u16 t[32][33];
  int bh = blockIdx.z, b = bh / NH, h = bh % NH;
  int t0 = blockIdx.x * 32, v0 = blockIdx.y * 32;
  int x = threadIdx.x, y = threadIdx.y;
  for (int i = 0; i < 4; i++)
    t[y + i * 8][x] = qkv[(size_t)(b * TT + t0 + y + i * 8) * 2304 + 1536 + h * HS + v0 + x];
  __syncthreads();
  for (int i = 0; i < 4; i++)
    vt[(size_t)(bh * HS + v0 + y + i * 8) * TT + t0 + x] = t[x][y + i * 8];
}

// ---------------- mask -> additive bias (log2 domain) ----------------------
__global__ __launch_bounds__(256) void maskbias(const int* __restrict__ mask,
                                                float* __restrict__ mb) {
  int i = blockIdx.x * 256 + threadIdx.x;
  mb[i] = mask[i] ? 0.f : -1e30f;
}

// ---------------- LayerNorm: fp32 row[768] -> bf16 ------------------------
__global__ __launch_bounds__(256) void ln_kernel(const float* __restrict__ x,
                                                 const float* __restrict__ g,
                                                 const float* __restrict__ bta,
                                                 u16* __restrict__ out) {
  int row = blockIdx.x;
  const float* xr = x + (size_t)row * D_MODEL;
  int tid = threadIdx.x;
  float v0 = xr[tid], v1 = xr[tid + 256], v2 = xr[tid + 512];
  float s = v0 + v1 + v2, sq = v0 * v0 + v1 * v1 + v2 * v2;
  for (int m = 1; m < 64; m <<= 1) { s += __shfl_xor(s, m); sq += __shfl_xor(sq, m); }
  __shared__ float ss[4], ssq[4];
  int w = tid >> 6;
  if ((tid & 63) == 0) { ss[w] = s; ssq[w] = sq; }
  __syncthreads();
  s = ss[0] + ss[1] + ss[2] + ss[3];
  sq = ssq[0] + ssq[1] + ssq[2] + ssq[3];
  float mean = s * (1.f / D_MODEL);
  float var = sq * (1.f / D_MODEL) - mean * mean;
  float rstd = rsqrtf(var + 1e-5f);
  u16* orow = out + (size_t)row * D_MODEL;
  orow[tid]       = f2bf((v0 - mean) * rstd * g[tid]       + bta[tid]);
  orow[tid + 256] = f2bf((v1 - mean) * rstd * g[tid + 256] + bta[tid + 256]);
  orow[tid + 512] = f2bf((v2 - mean) * rstd * g[tid + 512] + bta[tid + 512]);
}

// ---- partial-sum(4, bf16) + residual + bias + LayerNorm -> yv fp32, h2 bf16
__global__ __launch_bounds__(256) void red_wo_ln(
    const u16* __restrict__ p0, const u16* __restrict__ p1,
    const u16* __restrict__ p2, const u16* __restrict__ p3,
    const float* __restrict__ x, const float* __restrict__ bo,
    const float* __restrict__ g, const float* __restrict__ be,
    float* __restrict__ yv, u16* __restrict__ h2) {
  int row = blockIdx.x, tid = threadIdx.x;
  size_t base = (size_t)row * D_MODEL;
  float v[3];
  float s = 0.f, sq = 0.f;
  for (int i = 0; i < 3; i++) {
    int c = tid + i * 256;
    size_t idx = base + c;
    float t = bf2f(p0[idx]) + bf2f(p1[idx]) + bf2f(p2[idx]) + bf2f(p3[idx])
            + x[idx] + bo[c];
    v[i] = t; yv[idx] = t;
    s += t; sq += t * t;
  }
  for (int m = 1; m < 64; m <<= 1) { s += __shfl_xor(s, m); sq += __shfl_xor(sq, m); }
  __shared__ float ss[4], ssq[4];
  int w = tid >> 6;
  if ((tid & 63) == 0) { ss[w] = s; ssq[w] = sq; }
  __syncthreads();
  s = ss[0] + ss[1] + ss[2] + ss[3];
  sq = ssq[0] + ssq[1] + ssq[2] + ssq[3];
  float mean = s * (1.f / D_MODEL);
  float var = sq * (1.f / D_MODEL) - mean * mean;
  float rstd = rsqrtf(var + 1e-5f);
  for (int i = 0; i < 3; i++) {
    int c = tid + i * 256;
    h2[base + c] = f2bf((v[i] - mean) * rstd * g[c] + be[c]);
  }
}

// ---- partial-sum(3, bf16) + residual + bias -> out fp32 (vectorized x4) ---
__global__ __launch_bounds__(256) void red_ff2(
    const u16* __restrict__ p0, const u16* __restrict__ p1,
    const u16* __restrict__ p2, const float* __restrict__ yv,
    const float* __restrict__ bias, float* __restrict__ out) {
  size_t i = ((size_t)blockIdx.x * 256 + threadIdx.x) * 4;
  int col = (int)(i % D_MODEL);
  ushort4 a = *(const ushort4*)(p0 + i);
  ushort4 b = *(const ushort4*)(p1 + i);
  ushort4 c = *(const ushort4*)(p2 + i);
  float4 y = *(const float4*)(yv + i);
  float4 o;
  o.x = bf2f(a.x) + bf2f(b.x) + bf2f(c.x) + y.x + bias[col];
  o.y = bf2f(a.y) + bf2f(b.y) + bf2f(c.y) + y.y + bias[col + 1];
  o.z = bf2f(a.z) + bf2f(b.z) + bf2f(c.z) + y.z + bias[col + 2];
  o.w = bf2f(a.w) + bf2f(b.w) + bf2f(c.w) + y.w + bias[col + 3];
  *(float4*)(out + i) = o;
}

// ---------------- GEMM: C[M][N] = A[M][K](bf16) * Bt[N][K](bf16)^T ---------
// 128x128 tile, BK=32, 4 waves 2x2, 4x4 16x16x32 MFMA tiles per wave.
// Split-K via gridDim.z: each z handles K/gridDim.z contiguous k.
// EPI 0: bf16 out (cols<qn scaled by qs). EPI 2: bf16 relu(acc+bias).
// EPI 3: bf16 partial -> p[blockIdx.z].
template <int EPI>
__global__ __launch_bounds__(256) void gemm_bt(
    const u16* __restrict__ A, const u16* __restrict__ Bt,
    int M, int N, int K,
    u16* __restrict__ outb, const float* __restrict__ bias,
    float qs, int qn,
    u16* __restrict__ p0, u16* __restrict__ p1,
    u16* __restrict__ p2, u16* __restrict__ p3) {
  __shared__ __align__(16) u16 lA[128 * 32];
  __shared__ __align__(16) u16 lB[128 * 32];
  const int tid = threadIdx.x;
  const int lane = tid & 63, w = tid >> 6;
  const int quad = lane >> 4, l15 = lane & 15;
  const int wm = w >> 1, wn = w & 1;
  const int bm = blockIdx.y, bn = blockIdx.x;
  const int Ksub = K / gridDim.z;
  const int k0 = blockIdx.z * Ksub;

  fx4 acc[4][4] = {};

  for (int kt = k0; kt < k0 + Ksub; kt += 32) {
    __syncthreads();
    for (int t = 0; t < 2; t++) {
      int p = (w * 2 + t) * 64 + lane;
      int m = p >> 2, qp = p & 3;
      int ql = qp ^ ((m >> 1) & 3);
      async16(A + (size_t)(bm * 128 + m) * K + kt + ql * 8,
              (char*)lA + (w * 2 + t) * 1024);
    }
    for (int t = 0; t < 2; t++) {
      int p = (w * 2 + t) * 64 + lane;
      int n = p >> 2, qp = p & 3;
      int ql = qp ^ ((n >> 1) & 3);
      async16(Bt + (size_t)(bn * 128 + n) * K + kt + ql * 8,
              (char*)lB + (w * 2 + t) * 1024);
    }
    __syncthreads();
    s16x8 af[4], bfr[4];
    for (int i = 0; i < 4; i++) {
      int m = wm * 64 + i * 16 + l15;
      int phys = m * 4 + (quad ^ ((m >> 1) & 3));
      af[i] = *(const s16x8*)((const char*)lA + phys * 16);
    }
    for (int j = 0; j < 4; j++) {
      int n = wn * 64 + j * 16 + l15;
      int phys = n * 4 + (quad ^ ((n >> 1) & 3));
      bfr[j] = *(const s16x8*)((const char*)lB + phys * 16);
    }
    for (int i = 0; i < 4; i++)
      for (int j = 0; j < 4; j++)
        acc[i][j] = __builtin_amdgcn_mfma_f32_16x16x32_bf16(af[i], bfr[j], acc[i][j], 0, 0, 0);
  }

  u16* pb = nullptr;
  if (EPI == 3)
    pb = blockIdx.z == 0 ? p0 : blockIdx.z == 1 ? p1 : blockIdx.z == 2 ? p2 : p3;

  for (int i = 0; i < 4; i++)
    for (int j = 0; j < 4; j++)
      for (int r = 0; r < 4; r++) {
        int row = bm * 128 + wm * 64 + i * 16 + quad * 4 + r;
        int col = bn * 128 + wn * 64 + j * 16 + l15;
        float v = acc[i][j][r];
        if (EPI == 0) {
          float vv = (col < qn) ? v * qs : v;
          outb[(size_t)row * N + col] = f2bf(vv);
        } else if (EPI == 2) {
          outb[(size_t)row * N + col] = f2bf(fmaxf(v + bias[col], 0.f));
        } else {
          pb[(size_t)row * N + col] = f2bf(v);
        }
      }
}

// ---------------- Flash attention (fixed-shift softmax, log2 domain) -------
__global__ __launch_bounds__(256) void attn_kernel(
    const u16* __restrict__ qkv, const u16* __restrict__ vt,
    const float* __restrict__ maskadd, u16* __restrict__ out) {
  __shared__ __align__(16) u16 sQ[64 * 64];
  __shared__ __align__(16) u16 sK[64 * 64];
  __shared__ __align__(16) u16 sV[64 * 64];
  __shared__ __align__(16) u16 sP[4][16 * 64];
  const int bh = blockIdx.y, b = bh / NH, h = bh % NH;
  const int qt = blockIdx.x;
  const int tid = threadIdx.x, lane = tid & 63, w = tid >> 6;
  const int quad = lane >> 4, l15 = lane & 15;

  for (int t = 0; t < 2; t++) {
    int p = (w * 2 + t) * 64 + lane;
    int m = p >> 3, qp = p & 7, ql = qp ^ (m & 7);
    async16(qkv + (size_t)(b * TT + qt * 64 + m) * 2304 + h * HS + ql * 8,
            (char*)sQ + (w * 2 + t) * 1024);
  }
  __syncthreads();
  s16x8 aq[2];
  for (int kk = 0; kk < 2; kk++) {
    int m = w * 16 + l15;
    int phys = m * 8 + ((kk * 4 + quad) ^ (m & 7));
    aq[kk] = *(const s16x8*)((const char*)sQ + phys * 16);
  }

  float lsum[4] = {0.f, 0.f, 0.f, 0.f};
  fx4 o[4] = {};

  for (int kc = 0; kc < TT / 64; kc++) {
    __syncthreads();
    for (int t = 0; t < 2; t++) {
      int p = (w * 2 + t) * 64 + lane;
      int m = p >> 3, qp = p & 7, ql = qp ^ (m & 7);
      async16(qkv + (size_t)(b * TT + kc * 64 + m) * 2304 + D_MODEL + h * HS + ql * 8,
              (char*)sK + (w * 2 + t) * 1024);
    }
    for (int t = 0; t < 2; t++) {
      int p = (w * 2 + t) * 64 + lane;
      int m = p >> 3, qp = p & 7, ql = qp ^ (m & 7);
      async16(vt + (size_t)bh * HS * TT + (size_t)m * TT + kc * 64 + ql * 8,
              (char*)sV + (w * 2 + t) * 1024);
    }
    __syncthreads();

    for (int jn = 0; jn < 4; jn++) {
      float mb = maskadd[b * TT + kc * 64 + jn * 16 + l15];
      fx4 s = {mb, mb, mb, mb};
      for (int kk = 0; kk < 2; kk++) {
        int n = jn * 16 + l15;
        int phys = n * 8 + ((kk * 4 + quad) ^ (n & 7));
        s16x8 bk = *(const s16x8*)((const char*)sK + phys * 16);
        s = __builtin_amdgcn_mfma_f32_16x16x32_bf16(aq[kk], bk, s, 0, 0, 0);
      }
      for (int r = 0; r < 4; r++) {
        float p = __builtin_amdgcn_exp2f(s[r]);
        u16 pb = f2bf(p);
        lsum[r] += bf2f(pb);
        int row = quad * 4 + r, k = jn * 16 + l15;
        sP[w][row * 64 + ((k >> 3) ^ (row & 7)) * 8 + (k & 7)] = pb;
      }
    }
    for (int kk = 0; kk < 2; kk++) {
      int m = l15;
      int phys = m * 8 + ((kk * 4 + quad) ^ (m & 7));
      s16x8 ap = *(const s16x8*)((const char*)sP[w] + phys * 16);
      for (int jv = 0; jv < 4; jv++) {
        int n = jv * 16 + l15;
        int ph2 = n * 8 + ((kk * 4 + quad) ^ (n & 7));
        s16x8 bv = *(const s16x8*)((const char*)sV + ph2 * 16);
        o[jv] = __builtin_amdgcn_mfma_f32_16x16x32_bf16(ap, bv, o[jv], 0, 0, 0);
      }
    }
  }

  for (int mm = 1; mm < 16; mm <<= 1)
    for (int r = 0; r < 4; r++) lsum[r] += __shfl_xor(lsum[r], mm);

  for (int jv = 0; jv < 4; jv++)
    for (int r = 0; r < 4; r++) {
      int tok = qt * 64 + w * 16 + quad * 4 + r;
      out[(size_t)(b * TT + tok) * D_MODEL + h * HS + jv * 16 + l15] =
          f2bf(o[jv][r] / lsum[r]);
    }
}

extern "C" void kernel_launch(void* const* d_in, const int* in_sizes, int n_in,
                              void* d_out, int out_size, void* d_ws, size_t ws_size,
                              hipStream_t stream) {
  const float* x    = (const float*)d_in[0];
  const int*   mask = (const int*)d_in[1];
  const float* Wq   = (const float*)d_in[2];
  const float* Wk   = (const float*)d_in[3];
  const float* Wv   = (const float*)d_in[4];
  const float* Wo   = (const float*)d_in[5];
  const float* bo   = (const float*)d_in[6];
  const float* g1   = (const float*)d_in[7];
  const float* be1  = (const float*)d_in[8];
  const float* g2   = (const float*)d_in[9];
  const float* be2  = (const float*)d_in[10];
  const float* W1   = (const float*)d_in[11];
  const float* bb1  = (const float*)d_in[12];
  const float* W2   = (const float*)d_in[13];
  const float* bb2  = (const float*)d_in[14];
  float* out = (float*)d_out;
  char* ws = (char*)d_ws;

  // workspace carve (bytes), total 64,503,808
  u16*   WqkvT = (u16*)(ws + 0);           //  3,538,944  [2304][768]
  u16*   WoT   = (u16*)(ws + 3538944);     //  1,179,648  [768][768]
  u16*   W1T   = (u16*)(ws + 4718592);     //  4,718,592  [3072][768]
  u16*   W2T   = (u16*)(ws + 9437184);     //  4,718,592  [768][3072]
  u16*   h1    = (u16*)(ws + 14155776);    //  6,291,456  [4096][768]; h2 aliases
  u16*   QKV   = (u16*)(ws + 20447232);    // 18,874,368  [4096][2304]
  u16*   Vt    = (u16*)(ws + 39321600);    //  6,291,456  [24][64][2048]
  u16*   attn  = (u16*)(ws + 45613056);    //  6,291,456  [4096][768]
  float* yv    = (float*)(ws + 51904512);  // 12,582,912  [4096][768]
  float* mbias = yv;                       // dead before Wo writes yv
  u16*   h2    = h1;
  u16*   ff1   = QKV;                      // 25,165,824 spans QKV+Vt
  // Wo partials (4 x 6,291,456): QKV+Vt span, dead after attn, before ff1
  u16* pw0 = (u16*)(ws + 20447232);
  u16* pw1 = (u16*)(ws + 26738688);
  u16* pw2 = (u16*)(ws + 33030144);
  u16* pw3 = (u16*)(ws + 39321600);
  // FF2 partials (3 x 6,291,456): dead regions at FF2 time
  u16* pf0 = (u16*)(ws + 0);               // WqkvT+WoT+W1T-head (dead)
  u16* pf1 = (u16*)(ws + 14155776);        // h2 (dead after FF1)
  u16* pf2 = (u16*)(ws + 45613056);        // attn (dead after Wo)

  const float QS = 0.05205875399f;  // 768^-0.5 * log2(e)

  dim3 tb(32, 8);
  tconv3<<<dim3(24, 24, 3), tb, 0, stream>>>(Wq, Wk, Wv, WqkvT);
  tconv<<<dim3(24, 24), tb, 0, stream>>>(Wo, WoT, 768, 768);
  tconv<<<dim3(96, 24), tb, 0, stream>>>(W1, W1T, 768, 3072);
  tconv<<<dim3(24, 96), tb, 0, stream>>>(W2, W2T, 3072, 768);
  maskbias<<<16, 256, 0, stream>>>(mask, mbias);

  ln_kernel<<<4096, 256, 0, stream>>>(x, g1, be1, h1);
  gemm_bt<0><<<dim3(18, 32, 1), 256, 0, stream>>>(h1, WqkvT, 4096, 2304, 768,
      QKV, nullptr, QS, 768, nullptr, nullptr, nullptr, nullptr);
  vt_extract<<<dim3(64, 2, 24), tb, 0, stream>>>(QKV, Vt);
  attn_kernel<<<dim3(32, 24), 256, 0, stream>>>(QKV, Vt, mbias, attn);
  // Wo: split-K=4 -> 768 blocks (3/CU)
  gemm_bt<3><<<dim3(6, 32, 4), 256, 0, stream>>>(attn, WoT, 4096, 768, 768,
      nullptr, nullptr, 1.f, 0, pw0, pw1, pw2, pw3);
  red_wo_ln<<<4096, 256, 0, stream>>>(pw0, pw1, pw2, pw3, x, bo, g2, be2, yv, h2);
  gemm_bt<2><<<dim3(24, 32, 1), 256, 0, stream>>>(h2, W1T, 4096, 3072, 768,
      ff1, bb1, 1.f, 0, nullptr, nullptr, nullptr, nullptr);
  // FF2: split-K=3 -> 576 blocks (2.25/CU)
  gemm_bt<3><<<dim3(6, 32, 3), 256, 0, stream>>>(ff1, W2T, 4096, 768, 3072,
      nullptr, nullptr, 1.f, 0, pf0, pf1, pf2, nullptr);
  red_ff2<<<3072, 256, 0, stream>>>(pf0, pf1, pf2, yv, bb2, out);
}